// Round 6
// baseline (1723.589 us; speedup 1.0000x reference)
//
#include <hip/hip_runtime.h>
#include <math.h>

// clDice loss on MI355X (gfx950).
// soft_skeletonize = 20 iterations of:
//   m = minpool3(x); contour = relu(maxpool3(m) - m); x = relu(x - contour)
// Round-6: K=5 fused iterations per launch (8 launches total), row-streaming
// software pipeline. Round-5 was LDS-pipe-bound (full-row LDS staging:
// 8 b128 writes + 16 conflicted b32 reads per wave-iter ~= 1920 cyc/iter/CU
// = measured 95 us). Only the EDGE floats of each lane's float4 are ever read
// by neighbors, so exchange is now two float2{x_edge,m_edge} b64 writes +
// two b64 reads per stage (stride-1, conflict-free), double-buffered, with
// ONE barrier per row-iteration. Final reduction fused into last launch of
// each tensor.

#define IMG_H 1024
#define IMG_W 1024
#define IMG_N (IMG_H * IMG_W)
#define NIMG  16
#define BH    32                    // output rows per band
#define NBANDS (IMG_H / BH)         // 32
#define K     5                     // fused skeleton iterations per launch
#define EW    258                   // 256 lanes + 2 guard slots
#define ITER_PAIRS ((BH + 6 * K) / 2)   // 31 pairs = 62 row-iterations

__device__ __forceinline__ float min3f(float a, float b, float c) { return fminf(fminf(a, b), c); }
__device__ __forceinline__ float max3f(float a, float b, float c) { return fmaxf(fmaxf(a, b), c); }
__device__ __forceinline__ float4 f4(float v) { return make_float4(v, v, v, v); }

__device__ __forceinline__ float4 ldrow(const float* base, int y, int c)
{
    if ((unsigned)y < (unsigned)IMG_H)
        return *(const float4*)(base + (size_t)y * IMG_W + c);
    return f4(__builtin_huge_valf());
}

struct St {
    float4 hm1, hm2;    // hmin rows ri-2, ri-1
    float4 m2, m3;      // minpool rows ri-2, ri-3
    float4 q1, q2;      // hmax rows ri-4, ri-3
    float4 x1, x2, x3;  // input rows ri-1, ri-2, ri-3
    float4 xc;          // input row ri
};

// One pipeline stage at input row ri. Emits output row ri-3.
// Edge pairs: lp = left neighbor {x.w, m.w}; rp = right neighbor {x.x, m.x}.
template<int BUF>
__device__ __forceinline__ float4 stage_step(
    St& s, int ri, int t,
    const float2 (&eL)[2][EW], const float2 (&eR)[2][EW])
{
    const float INF = __builtin_huge_valf();
    float2 lp = eR[BUF][t];          // left neighbor's edges (guard at t=0)
    float2 rp = eL[BUF][t + 2];      // right neighbor's edges (guard at 257)
    // h-min3 of input row ri
    float4 h;
    h.x = min3f(lp.x,   s.xc.x, s.xc.y);
    h.y = min3f(s.xc.x, s.xc.y, s.xc.z);
    h.z = min3f(s.xc.y, s.xc.z, s.xc.w);
    h.w = min3f(s.xc.z, s.xc.w, rp.x);
    // v-min3 -> m row ri-1 (-inf when row outside image: maxpool padding)
    float4 m;
    if ((unsigned)(ri - 1) < (unsigned)IMG_H) {
        m.x = min3f(s.hm1.x, s.hm2.x, h.x);
        m.y = min3f(s.hm1.y, s.hm2.y, h.y);
        m.z = min3f(s.hm1.z, s.hm2.z, h.z);
        m.w = min3f(s.hm1.w, s.hm2.w, h.w);
    } else {
        m = f4(-INF);
    }
    // h-max3 of m row ri-2 (center in reg m2, neighbor edges from prev iter)
    float4 q;
    q.x = max3f(lp.y,   s.m2.x, s.m2.y);
    q.y = max3f(s.m2.x, s.m2.y, s.m2.z);
    q.z = max3f(s.m2.y, s.m2.z, s.m2.w);
    q.w = max3f(s.m2.z, s.m2.w, rp.y);
    // v-max3 -> M row ri-3; contour = relu(M - m); out = relu(x - contour)
    float4 M;
    M.x = max3f(s.q1.x, s.q2.x, q.x);
    M.y = max3f(s.q1.y, s.q2.y, q.y);
    M.z = max3f(s.q1.z, s.q2.z, q.z);
    M.w = max3f(s.q1.w, s.q2.w, q.w);
    float4 e;
    e.x = fmaxf(s.x3.x - fmaxf(M.x - s.m3.x, 0.f), 0.f);
    e.y = fmaxf(s.x3.y - fmaxf(M.y - s.m3.y, 0.f), 0.f);
    e.z = fmaxf(s.x3.z - fmaxf(M.z - s.m3.z, 0.f), 0.f);
    e.w = fmaxf(s.x3.w - fmaxf(M.w - s.m3.w, 0.f), 0.f);
    // ring shifts
    s.hm1 = s.hm2; s.hm2 = h;
    s.m3  = s.m2;  s.m2  = m;
    s.q1  = s.q2;  s.q2  = q;
    s.x3  = s.x2;  s.x2  = s.x1; s.x1 = s.xc;
    return e;
}

template<int BUF>
__device__ __forceinline__ void iter_step(
    int y, int t, int c, int r0, St (&st)[K],
    const float* __restrict__ s, float* __restrict__ o,
    const float* __restrict__ other, float& a1, float& a2,
    float2 (&eL)[K][2][EW], float2 (&eR)[K][2][EW])
{
    const float INF = __builtin_huge_valf();
    float4 xnext = ldrow(s, y + 1, c);       // stage-0 prefetch
    __syncthreads();                         // prev-iter edge writes visible
    float4 em[K];
    #pragma unroll
    for (int k = 0; k < K; ++k)
        em[k] = stage_step<BUF>(st[k], y - 4 * k, t, eL[k], eR[k]);
    // chain emits to next stage's input (+inf for out-of-image rows)
    #pragma unroll
    for (int k = K - 1; k >= 1; --k) {
        int er = y - 4 * (k - 1) - 3;        // row emitted by stage k-1
        st[k].xc = ((unsigned)er < (unsigned)IMG_H) ? em[k - 1] : f4(INF);
    }
    st[0].xc = xnext;
    // edge writes for next iteration (new xc + this iter's m, now in m2)
    #pragma unroll
    for (int k = 0; k < K; ++k) {
        eL[k][BUF ^ 1][t + 1] = make_float2(st[k].xc.x, st[k].m2.x);
        eR[k][BUF ^ 1][t + 1] = make_float2(st[k].xc.w, st[k].m2.w);
    }
    // final-stage store (+ optional fused reduction)
    int orow = y - (4 * (K - 1) + 3);
    if ((unsigned)(orow - r0) < (unsigned)BH) {
        float4 e = em[K - 1];
        *(float4*)(o + (size_t)orow * IMG_W + c) = e;
        if (other) {
            float4 ov = *(const float4*)(other + (size_t)orow * IMG_W + c);
            a1 += e.x * ov.x + e.y * ov.y + e.z * ov.z + e.w * ov.w;
            a2 += e.x + e.y + e.z + e.w;
        }
    }
}

__global__ __launch_bounds__(256, 2) void skel5(
    const float* __restrict__ src, float* __restrict__ dst,
    const float* __restrict__ other, double* __restrict__ acc2)
{
    __shared__ float2 eL[K][2][EW];   // {x.x, m.x} per lane, slot t+1
    __shared__ float2 eR[K][2][EW];   // {x.w, m.w} per lane, slot t+1
    __shared__ double l1[4], l2[4];

    const int t = threadIdx.x, c = 4 * t;
    const int r0 = blockIdx.x * BH;
    const float* s = src + (size_t)blockIdx.y * IMG_N;
    float*       o = dst + (size_t)blockIdx.y * IMG_N;
    const float INF = __builtin_huge_valf();

    if (t < K) {
        #pragma unroll
        for (int b = 0; b < 2; ++b) {
            eR[t][b][0]      = make_float2(INF, -INF);   // left image guard
            eL[t][b][EW - 1] = make_float2(INF, -INF);   // right image guard
        }
    }

    St st[K];
    #pragma unroll
    for (int k = 0; k < K; ++k) {
        st[k].hm1 = st[k].hm2 = f4(INF);
        st[k].m2 = st[k].m3 = f4(-INF);
        st[k].q1 = st[k].q2 = f4(-INF);
        st[k].x1 = st[k].x2 = st[k].x3 = f4(INF);
        st[k].xc = f4(INF);
    }
    st[0].xc = ldrow(s, r0 - 2 * K, c);      // first stage-0 input row

    // prologue edge write into buf 0 (consumed by first iteration)
    #pragma unroll
    for (int k = 0; k < K; ++k) {
        eL[k][0][t + 1] = make_float2(st[k].xc.x, st[k].m2.x);
        eR[k][0][t + 1] = make_float2(st[k].xc.w, st[k].m2.w);
    }

    float a1 = 0.f, a2 = 0.f;
    const int y0 = r0 - 2 * K;               // even -> BUF parity compile-time
    for (int p = 0; p < ITER_PAIRS; ++p) {
        int y = y0 + 2 * p;
        iter_step<0>(y,     t, c, r0, st, s, o, other, a1, a2, eL, eR);
        iter_step<1>(y + 1, t, c, r0, st, s, o, other, a1, a2, eL, eR);
    }

    if (other) {                             // fused reduction epilogue
        double d1 = a1, d2 = a2;
        for (int off = 32; off; off >>= 1) {
            d1 += __shfl_down(d1, off);
            d2 += __shfl_down(d2, off);
        }
        const int w = t >> 6;
        if ((t & 63) == 0) { l1[w] = d1; l2[w] = d2; }
        __syncthreads();
        if (t == 0) {
            atomicAdd(&acc2[0], l1[0] + l1[1] + l1[2] + l1[3]);
            atomicAdd(&acc2[1], l2[0] + l2[1] + l2[2] + l2[3]);
        }
    }
}

__global__ void zero_acc(double* __restrict__ acc)
{
    if (threadIdx.x < 4) acc[threadIdx.x] = 0.0;
}

__global__ void finalize(const double* __restrict__ acc, float* __restrict__ out)
{
    double iflat = (acc[0] + 1.0) / (acc[1] + 1.0);
    double tflat = (acc[2] + 1.0) / (acc[3] + 1.0);
    double inter = iflat * tflat;
    out[0] = (float)(1.0 - 2.0 * inter / (iflat + tflat));
}

extern "C" void kernel_launch(void* const* d_in, const int* in_sizes, int n_in,
                              void* d_out, int out_size, void* d_ws, size_t ws_size,
                              hipStream_t stream)
{
    const float* pred = (const float*)d_in[0];
    const float* gt   = (const float*)d_in[1];

    double* acc  = (double*)d_ws;                   // 4 doubles @ +0
    float*  bufA = (float*)((char*)d_ws + 256);     // 16 images
    float*  bufB = bufA + (size_t)NIMG * IMG_N;     // 16 images

    zero_acc<<<1, 64, 0, stream>>>(acc);

    dim3 grid(NBANDS, NIMG);                        // 32 bands x 16 images

    // ---- pred skeleton: 4 launches x 5 fused iterations = 20 ----
    skel5<<<grid, 256, 0, stream>>>(pred, bufA, nullptr, nullptr);
    skel5<<<grid, 256, 0, stream>>>(bufA, bufB, nullptr, nullptr);
    skel5<<<grid, 256, 0, stream>>>(bufB, bufA, nullptr, nullptr);
    skel5<<<grid, 256, 0, stream>>>(bufA, bufB, gt, acc);        // + iflat sums

    // ---- gt skeleton ----
    skel5<<<grid, 256, 0, stream>>>(gt,   bufA, nullptr, nullptr);
    skel5<<<grid, 256, 0, stream>>>(bufA, bufB, nullptr, nullptr);
    skel5<<<grid, 256, 0, stream>>>(bufB, bufA, nullptr, nullptr);
    skel5<<<grid, 256, 0, stream>>>(bufA, bufB, pred, acc + 2);  // + tflat sums

    finalize<<<1, 1, 0, stream>>>(acc, (float*)d_out);
}

// Round 7
// 795.087 us; speedup vs baseline: 2.1678x; 2.1678x over previous
//
#include <hip/hip_runtime.h>
#include <math.h>

// clDice loss on MI355X (gfx950).
// soft_skeletonize = 20 iterations of:
//   m = minpool3(x); contour = relu(maxpool3(m) - m); x = relu(x - contour)
// Round-7: K=4 fused iterations per launch (10 launches), row-streaming
// software pipeline with EDGE-ONLY LDS exchange (round-6's win: float2
// {x_edge,m_edge} per side per stage, double-buffered, 1 barrier/row-iter,
// conflict-free). Round-6's K=5 overflowed the 256-reg/wave budget at
// 2 waves/SIMD -> scratch spills (WRITE_SIZE 66 -> 413 MB, 2x slowdown);
// K=4 state (~160 regs) fits in the unified VGPR+AGPR file. Emits are
// chained in reverse stage order (no em[] temp array).
// Final reduction fused into the last launch of each tensor.

#define IMG_H 1024
#define IMG_W 1024
#define IMG_N (IMG_H * IMG_W)
#define NIMG  16
#define BH    32                    // output rows per band
#define NBANDS (IMG_H / BH)         // 32
#define K     4                     // fused skeleton iterations per launch
#define EW    258                   // 256 lanes + 2 guard slots
#define ITER_PAIRS ((BH + 6 * K) / 2)   // 28 pairs = 56 row-iterations

__device__ __forceinline__ float min3f(float a, float b, float c) { return fminf(fminf(a, b), c); }
__device__ __forceinline__ float max3f(float a, float b, float c) { return fmaxf(fmaxf(a, b), c); }
__device__ __forceinline__ float4 f4(float v) { return make_float4(v, v, v, v); }

__device__ __forceinline__ float4 ldrow(const float* base, int y, int c)
{
    if ((unsigned)y < (unsigned)IMG_H)
        return *(const float4*)(base + (size_t)y * IMG_W + c);
    return f4(__builtin_huge_valf());
}

struct St {
    float4 hm1, hm2;    // hmin rows ri-2, ri-1
    float4 m2, m3;      // minpool rows ri-2, ri-3
    float4 q1, q2;      // hmax rows ri-4, ri-3
    float4 x1, x2, x3;  // input rows ri-1, ri-2, ri-3
    float4 xc;          // input row ri
};

// One pipeline stage at input row ri. Returns output row ri-3.
// lp = left neighbor {x.w, m.w}; rp = right neighbor {x.x, m.x}.
template<int BUF>
__device__ __forceinline__ float4 stage_step(
    St& s, int ri, int t,
    const float2 (&eL)[2][EW], const float2 (&eR)[2][EW])
{
    const float INF = __builtin_huge_valf();
    float2 lp = eR[BUF][t];          // left neighbor's edges (guard at t=0)
    float2 rp = eL[BUF][t + 2];      // right neighbor's edges (guard at 257)
    // h-min3 of input row ri
    float4 h;
    h.x = min3f(lp.x,   s.xc.x, s.xc.y);
    h.y = min3f(s.xc.x, s.xc.y, s.xc.z);
    h.z = min3f(s.xc.y, s.xc.z, s.xc.w);
    h.w = min3f(s.xc.z, s.xc.w, rp.x);
    // v-min3 -> m row ri-1 (-inf when row outside image: maxpool padding)
    float4 m;
    if ((unsigned)(ri - 1) < (unsigned)IMG_H) {
        m.x = min3f(s.hm1.x, s.hm2.x, h.x);
        m.y = min3f(s.hm1.y, s.hm2.y, h.y);
        m.z = min3f(s.hm1.z, s.hm2.z, h.z);
        m.w = min3f(s.hm1.w, s.hm2.w, h.w);
    } else {
        m = f4(-INF);
    }
    // h-max3 of m row ri-2 (center in reg m2, neighbor edges from prev iter)
    float4 q;
    q.x = max3f(lp.y,   s.m2.x, s.m2.y);
    q.y = max3f(s.m2.x, s.m2.y, s.m2.z);
    q.z = max3f(s.m2.y, s.m2.z, s.m2.w);
    q.w = max3f(s.m2.z, s.m2.w, rp.y);
    // v-max3 -> M row ri-3; contour = relu(M - m); out = relu(x - contour)
    float4 M;
    M.x = max3f(s.q1.x, s.q2.x, q.x);
    M.y = max3f(s.q1.y, s.q2.y, q.y);
    M.z = max3f(s.q1.z, s.q2.z, q.z);
    M.w = max3f(s.q1.w, s.q2.w, q.w);
    float4 e;
    e.x = fmaxf(s.x3.x - fmaxf(M.x - s.m3.x, 0.f), 0.f);
    e.y = fmaxf(s.x3.y - fmaxf(M.y - s.m3.y, 0.f), 0.f);
    e.z = fmaxf(s.x3.z - fmaxf(M.z - s.m3.z, 0.f), 0.f);
    e.w = fmaxf(s.x3.w - fmaxf(M.w - s.m3.w, 0.f), 0.f);
    // ring shifts
    s.hm1 = s.hm2; s.hm2 = h;
    s.m3  = s.m2;  s.m2  = m;
    s.q1  = s.q2;  s.q2  = q;
    s.x3  = s.x2;  s.x2  = s.x1; s.x1 = s.xc;
    return e;
}

template<int BUF>
__device__ __forceinline__ void iter_step(
    int y, int t, int c, int r0, St (&st)[K],
    const float* __restrict__ s, float* __restrict__ o,
    const float* __restrict__ other, float& a1, float& a2,
    float2 (&eL)[K][2][EW], float2 (&eR)[K][2][EW])
{
    const float INF = __builtin_huge_valf();
    float4 xnext = ldrow(s, y + 1, c);       // stage-0 prefetch
    __syncthreads();                         // prev-iter edge writes visible

    // stages in REVERSE order: stage k consumes its old xc, then receives
    // stage k-1's emit; only one emit temp live at a time.
    float4 eK = stage_step<BUF>(st[K - 1], y - 4 * (K - 1), t, eL[K - 1], eR[K - 1]);
    #pragma unroll
    for (int k = K - 2; k >= 0; --k) {
        float4 e = stage_step<BUF>(st[k], y - 4 * k, t, eL[k], eR[k]);
        int er = y - 4 * k - 3;              // row emitted by stage k
        st[k + 1].xc = ((unsigned)er < (unsigned)IMG_H) ? e : f4(INF);
    }
    st[0].xc = xnext;

    // edge writes for next iteration (new xc + this iter's m, now in m2)
    #pragma unroll
    for (int k = 0; k < K; ++k) {
        eL[k][BUF ^ 1][t + 1] = make_float2(st[k].xc.x, st[k].m2.x);
        eR[k][BUF ^ 1][t + 1] = make_float2(st[k].xc.w, st[k].m2.w);
    }

    // final-stage store (+ optional fused reduction)
    int orow = y - (4 * (K - 1) + 3);
    if ((unsigned)(orow - r0) < (unsigned)BH) {
        *(float4*)(o + (size_t)orow * IMG_W + c) = eK;
        if (other) {
            float4 ov = *(const float4*)(other + (size_t)orow * IMG_W + c);
            a1 += eK.x * ov.x + eK.y * ov.y + eK.z * ov.z + eK.w * ov.w;
            a2 += eK.x + eK.y + eK.z + eK.w;
        }
    }
}

__global__ __launch_bounds__(256, 2) void skel4(
    const float* __restrict__ src, float* __restrict__ dst,
    const float* __restrict__ other, double* __restrict__ acc2)
{
    __shared__ float2 eL[K][2][EW];   // {x.x, m.x} per lane, slot t+1
    __shared__ float2 eR[K][2][EW];   // {x.w, m.w} per lane, slot t+1
    __shared__ double l1[4], l2[4];

    const int t = threadIdx.x, c = 4 * t;
    const int r0 = blockIdx.x * BH;
    const float* s = src + (size_t)blockIdx.y * IMG_N;
    float*       o = dst + (size_t)blockIdx.y * IMG_N;
    const float INF = __builtin_huge_valf();

    if (t < K) {
        #pragma unroll
        for (int b = 0; b < 2; ++b) {
            eR[t][b][0]      = make_float2(INF, -INF);   // left image guard
            eL[t][b][EW - 1] = make_float2(INF, -INF);   // right image guard
        }
    }

    St st[K];
    #pragma unroll
    for (int k = 0; k < K; ++k) {
        st[k].hm1 = st[k].hm2 = f4(INF);
        st[k].m2 = st[k].m3 = f4(-INF);
        st[k].q1 = st[k].q2 = f4(-INF);
        st[k].x1 = st[k].x2 = st[k].x3 = f4(INF);
        st[k].xc = f4(INF);
    }
    st[0].xc = ldrow(s, r0 - 2 * K, c);      // first stage-0 input row

    // prologue edge write into buf 0 (consumed by first iteration)
    #pragma unroll
    for (int k = 0; k < K; ++k) {
        eL[k][0][t + 1] = make_float2(st[k].xc.x, st[k].m2.x);
        eR[k][0][t + 1] = make_float2(st[k].xc.w, st[k].m2.w);
    }

    float a1 = 0.f, a2 = 0.f;
    const int y0 = r0 - 2 * K;               // even -> BUF parity compile-time
    for (int p = 0; p < ITER_PAIRS; ++p) {
        int y = y0 + 2 * p;
        iter_step<0>(y,     t, c, r0, st, s, o, other, a1, a2, eL, eR);
        iter_step<1>(y + 1, t, c, r0, st, s, o, other, a1, a2, eL, eR);
    }

    if (other) {                             // fused reduction epilogue
        double d1 = a1, d2 = a2;
        for (int off = 32; off; off >>= 1) {
            d1 += __shfl_down(d1, off);
            d2 += __shfl_down(d2, off);
        }
        const int w = t >> 6;
        if ((t & 63) == 0) { l1[w] = d1; l2[w] = d2; }
        __syncthreads();
        if (t == 0) {
            atomicAdd(&acc2[0], l1[0] + l1[1] + l1[2] + l1[3]);
            atomicAdd(&acc2[1], l2[0] + l2[1] + l2[2] + l2[3]);
        }
    }
}

__global__ void zero_acc(double* __restrict__ acc)
{
    if (threadIdx.x < 4) acc[threadIdx.x] = 0.0;
}

__global__ void finalize(const double* __restrict__ acc, float* __restrict__ out)
{
    double iflat = (acc[0] + 1.0) / (acc[1] + 1.0);
    double tflat = (acc[2] + 1.0) / (acc[3] + 1.0);
    double inter = iflat * tflat;
    out[0] = (float)(1.0 - 2.0 * inter / (iflat + tflat));
}

extern "C" void kernel_launch(void* const* d_in, const int* in_sizes, int n_in,
                              void* d_out, int out_size, void* d_ws, size_t ws_size,
                              hipStream_t stream)
{
    const float* pred = (const float*)d_in[0];
    const float* gt   = (const float*)d_in[1];

    double* acc  = (double*)d_ws;                   // 4 doubles @ +0
    float*  bufA = (float*)((char*)d_ws + 256);     // 16 images
    float*  bufB = bufA + (size_t)NIMG * IMG_N;     // 16 images

    zero_acc<<<1, 64, 0, stream>>>(acc);

    dim3 grid(NBANDS, NIMG);                        // 32 bands x 16 images

    // ---- pred skeleton: 5 launches x 4 fused iterations = 20 ----
    skel4<<<grid, 256, 0, stream>>>(pred, bufA, nullptr, nullptr);
    skel4<<<grid, 256, 0, stream>>>(bufA, bufB, nullptr, nullptr);
    skel4<<<grid, 256, 0, stream>>>(bufB, bufA, nullptr, nullptr);
    skel4<<<grid, 256, 0, stream>>>(bufA, bufB, nullptr, nullptr);
    skel4<<<grid, 256, 0, stream>>>(bufB, bufA, gt, acc);        // + iflat sums

    // ---- gt skeleton ----
    skel4<<<grid, 256, 0, stream>>>(gt,   bufB, nullptr, nullptr);
    skel4<<<grid, 256, 0, stream>>>(bufB, bufA, nullptr, nullptr);
    skel4<<<grid, 256, 0, stream>>>(bufA, bufB, nullptr, nullptr);
    skel4<<<grid, 256, 0, stream>>>(bufB, bufA, nullptr, nullptr);
    skel4<<<grid, 256, 0, stream>>>(bufA, bufB, pred, acc + 2);  // + tflat sums

    finalize<<<1, 1, 0, stream>>>(acc, (float*)d_out);
}